// Round 2
// baseline (78.312 us; speedup 1.0000x reference)
//
#include <hip/hip_runtime.h>

#define N_TIME 112
#define BATCH  262144
#define NV     (N_TIME / 4)   // 28 float4 per row
#define CHUNK  7              // 7 float4 = 28 elems = 1/4 row

__device__ __forceinline__ float sig(float cap, float c, float vp,
                                     float kd, float invT10) {
    const float TR     = 0.005f;
    const float R1     = 4.5f;
    const float SINA20 = 20.0f * 0.25881904510252074f;  // 20*sin(15deg)
    const float COSA   = 0.96592582628906829f;          // cos(15deg)
    float ct  = vp * cap + kd * c;
    float e   = __expf(-TR * (invT10 + R1 * ct));
    return (1.0f - e) * SINA20 * __builtin_amdgcn_rcpf(1.0f - e * COSA);
}

__device__ __forceinline__ void proc_chunk(float4* x, float& c, float decay,
                                           float vp, float kd, float invT10) {
    #pragma unroll
    for (int j = 0; j < CHUNK; ++j) {
        float4 v = x[j];
        float4 y;
        c = c * decay + v.x;  y.x = sig(v.x, c, vp, kd, invT10);
        c = c * decay + v.y;  y.y = sig(v.y, c, vp, kd, invT10);
        c = c * decay + v.z;  y.z = sig(v.z, c, vp, kd, invT10);
        c = c * decay + v.w;  y.w = sig(v.w, c, vp, kd, invT10);
        x[j] = y;
    }
}

__global__ __launch_bounds__(256) void etofts_kernel(
    const float* __restrict__ ktrans_p,
    const float* __restrict__ vp_p,
    const float* __restrict__ ve_p,
    const float* __restrict__ T10_p,
    const float* __restrict__ cap_p,
    float* __restrict__ out_p)
{
    const int row = blockIdx.x * blockDim.x + threadIdx.x;

    const float DELTT = 4.0f / 60.0f;

    const float ktrans = ktrans_p[row];
    const float vp     = vp_p[row];
    const float ve     = ve_p[row];
    const float invT10 = __builtin_amdgcn_rcpf(T10_p[row]);

    const float decay = __expf(-ktrans / ve * DELTT);
    const float kd    = ktrans * DELTT;

    const float4* cap = reinterpret_cast<const float4*>(cap_p) + (size_t)row * NV;
    float4*       out = reinterpret_cast<float4*>(out_p)       + (size_t)row * NV;

    float4 x0[CHUNK], x1[CHUNK], x2[CHUNK], x3[CHUNK];

    // Issue 14 loads up front (2 chunks), keep pipeline >= 2 chunks deep.
    #pragma unroll
    for (int j = 0; j < CHUNK; ++j) x0[j] = cap[j];
    #pragma unroll
    for (int j = 0; j < CHUNK; ++j) x1[j] = cap[CHUNK + j];

    float c = 0.0f;

    proc_chunk(x0, c, decay, vp, kd, invT10);       // waits on x0 only
    #pragma unroll
    for (int j = 0; j < CHUNK; ++j) x2[j] = cap[2 * CHUNK + j];
    #pragma unroll
    for (int j = 0; j < CHUNK; ++j) out[j] = x0[j]; // 7 back-to-back stores

    proc_chunk(x1, c, decay, vp, kd, invT10);
    #pragma unroll
    for (int j = 0; j < CHUNK; ++j) x3[j] = cap[3 * CHUNK + j];
    #pragma unroll
    for (int j = 0; j < CHUNK; ++j) out[CHUNK + j] = x1[j];

    proc_chunk(x2, c, decay, vp, kd, invT10);
    #pragma unroll
    for (int j = 0; j < CHUNK; ++j) out[2 * CHUNK + j] = x2[j];

    proc_chunk(x3, c, decay, vp, kd, invT10);
    #pragma unroll
    for (int j = 0; j < CHUNK; ++j) out[3 * CHUNK + j] = x3[j];
}

extern "C" void kernel_launch(void* const* d_in, const int* in_sizes, int n_in,
                              void* d_out, int out_size, void* d_ws, size_t ws_size,
                              hipStream_t stream) {
    const float* ktrans = (const float*)d_in[0];
    const float* vp     = (const float*)d_in[1];
    const float* ve     = (const float*)d_in[2];
    const float* T10    = (const float*)d_in[3];
    const float* CAp    = (const float*)d_in[4];
    float* out = (float*)d_out;

    dim3 block(256);
    dim3 grid(BATCH / 256);
    etofts_kernel<<<grid, block, 0, stream>>>(ktrans, vp, ve, T10, CAp, out);
}

// Round 3
// 64.480 us; speedup vs baseline: 1.2145x; 1.2145x over previous
//
#include <hip/hip_runtime.h>

#define N_TIME 112
#define BATCH  262144
#define ROWS   256            // rows per block (= block size)
#define CPC    28             // columns per chunk
#define NCH    4              // chunks per row (4*28 = 112)
#define LDP    (CPC + 1)      // padded LDS row: 29 words -> conflict-free column reads
#define F4PC   7              // float4 per row-chunk
#define TOTF4  (ROWS * F4PC)  // 1792 float4 per chunk per block

__device__ __forceinline__ float sig(float cap, float c, float vp,
                                     float kd, float invT10) {
    const float TR     = 0.005f;
    const float R1     = 4.5f;
    const float SINA20 = 20.0f * 0.25881904510252074f;  // 20*sin(15deg)
    const float COSA   = 0.96592582628906829f;          // cos(15deg)
    float ct = vp * cap + kd * c;
    float e  = __expf(-TR * (invT10 + R1 * ct));
    return (1.0f - e) * SINA20 * __builtin_amdgcn_rcpf(1.0f - e * COSA);
}

__global__ __launch_bounds__(256) void etofts_kernel(
    const float* __restrict__ ktrans_p,
    const float* __restrict__ vp_p,
    const float* __restrict__ ve_p,
    const float* __restrict__ T10_p,
    const float* __restrict__ cap_p,
    float* __restrict__ out_p)
{
    __shared__ float tile[ROWS][LDP];   // 29696 B

    const int t    = threadIdx.x;
    const int row0 = blockIdx.x * ROWS;
    const int grow = row0 + t;

    const float DELTT  = 4.0f / 60.0f;
    const float ktrans = ktrans_p[grow];
    const float vp     = vp_p[grow];
    const float ve     = ve_p[grow];
    const float invT10 = __builtin_amdgcn_rcpf(T10_p[grow]);
    const float decay  = __expf(-ktrans / ve * DELTT);
    const float kd     = ktrans * DELTT;

    const float4* capv = reinterpret_cast<const float4*>(cap_p);
    float4*       outv = reinterpret_cast<float4*>(out_p);

    // Per-lane flat-index mapping for cooperative (coalesced) chunk I/O.
    int rr[F4PC], jj[F4PC];
    #pragma unroll
    for (int k = 0; k < F4PC; ++k) {
        int f = t + k * ROWS;       // 0 .. 1791
        rr[k] = f / F4PC;           // row within block
        jj[k] = f % F4PC;           // float4 within chunk
    }

    float4 pre[F4PC];
    // Prefetch chunk 0.
    #pragma unroll
    for (int k = 0; k < F4PC; ++k)
        pre[k] = capv[(size_t)(row0 + rr[k]) * (N_TIME / 4) + jj[k]];

    float cst = 0.0f;

    for (int ch = 0; ch < NCH; ++ch) {
        // Drain prefetch registers into LDS.
        #pragma unroll
        for (int k = 0; k < F4PC; ++k) {
            float* dst = &tile[rr[k]][jj[k] * 4];
            dst[0] = pre[k].x; dst[1] = pre[k].y;
            dst[2] = pre[k].z; dst[3] = pre[k].w;
        }
        __syncthreads();            // tile ready for compute

        // Issue next chunk's global loads; they fly during compute.
        if (ch + 1 < NCH) {
            #pragma unroll
            for (int k = 0; k < F4PC; ++k)
                pre[k] = capv[(size_t)(row0 + rr[k]) * (N_TIME / 4)
                              + (ch + 1) * F4PC + jj[k]];
        }

        // IIR + signal on this thread's own row, in place.
        float* my = tile[t];
        #pragma unroll
        for (int k = 0; k < CPC; ++k) {
            float x = my[k];
            cst = cst * decay + x;
            my[k] = sig(x, cst, vp, kd, invT10);
        }
        __syncthreads();            // all rows computed

        // Cooperative coalesced full-line store.
        #pragma unroll
        for (int k = 0; k < F4PC; ++k) {
            const float* src = &tile[rr[k]][jj[k] * 4];
            float4 v = make_float4(src[0], src[1], src[2], src[3]);
            outv[(size_t)(row0 + rr[k]) * (N_TIME / 4) + ch * F4PC + jj[k]] = v;
        }
        __syncthreads();            // tile free for next chunk's ds_writes
    }
}

extern "C" void kernel_launch(void* const* d_in, const int* in_sizes, int n_in,
                              void* d_out, int out_size, void* d_ws, size_t ws_size,
                              hipStream_t stream) {
    const float* ktrans = (const float*)d_in[0];
    const float* vp     = (const float*)d_in[1];
    const float* ve     = (const float*)d_in[2];
    const float* T10    = (const float*)d_in[3];
    const float* CAp    = (const float*)d_in[4];
    float* out = (float*)d_out;

    dim3 block(ROWS);
    dim3 grid(BATCH / ROWS);
    etofts_kernel<<<grid, block, 0, stream>>>(ktrans, vp, ve, T10, CAp, out);
}

// Round 4
// 52.609 us; speedup vs baseline: 1.4885x; 1.2256x over previous
//
#include <hip/hip_runtime.h>

#define N_TIME  112
#define BATCH   262144
#define NF4ROW  28      // float4 per full row (112 cols)
#define F4PC    4       // float4 per row-chunk (16 cols = 64 B, line-aligned)
#define NCH     7       // chunks per row
#define LROW    5       // padded LDS row pitch in float4 (20 words, bank-balanced)

__device__ __forceinline__ float sig(float cap, float c, float vp,
                                     float kd, float invT10) {
    const float TR     = 0.005f;
    const float R1     = 4.5f;
    const float SINA20 = 20.0f * 0.25881904510252074f;  // 20*sin(15deg)
    const float COSA   = 0.96592582628906829f;          // cos(15deg)
    float ct = vp * cap + kd * c;
    float e  = __expf(-TR * (invT10 + R1 * ct));
    return (1.0f - e) * SINA20 * __builtin_amdgcn_rcpf(1.0f - e * COSA);
}

__global__ __launch_bounds__(256) void etofts_kernel(
    const float* __restrict__ ktrans_p,
    const float* __restrict__ vp_p,
    const float* __restrict__ ve_p,
    const float* __restrict__ T10_p,
    const float* __restrict__ cap_p,
    float* __restrict__ out_p)
{
    // Wave-private tiles: 64 rows x 5 float4 (pitch-padded) = 5120 B per wave.
    // No __syncthreads anywhere -> no vmcnt(0) drains; prefetch stays in flight.
    __shared__ float4 tile[4][64 * LROW];   // 20480 B per block

    const int tid  = threadIdx.x;
    const int w    = tid >> 6;
    const int lane = tid & 63;
    const int row0 = blockIdx.x * 256 + w * 64;   // this wave's first row
    const int grow = row0 + lane;

    const float DELTT  = 4.0f / 60.0f;
    const float ktrans = ktrans_p[grow];
    const float vp     = vp_p[grow];
    const float ve     = ve_p[grow];
    const float invT10 = __builtin_amdgcn_rcpf(T10_p[grow]);
    const float decay  = __expf(-ktrans / ve * DELTT);
    const float kd     = ktrans * DELTT;

    const float4* capv = reinterpret_cast<const float4*>(cap_p);
    float4*       outv = reinterpret_cast<float4*>(out_p);
    float4*       wt   = tile[w];

    // Cooperative mapping: flat f = lane + 64k covers 64 rows x 4 float4.
    // rr = f>>2 (row in wave), jj = f&3 (float4 within chunk).
    int    slot[F4PC];      // LDS float4 index (padded pitch)
    size_t gidx[F4PC];      // global float4 index for chunk 0
    #pragma unroll
    for (int k = 0; k < F4PC; ++k) {
        int f  = lane + (k << 6);
        int rr = f >> 2;
        int jj = f & 3;
        slot[k] = rr * LROW + jj;
        gidx[k] = (size_t)(row0 + rr) * NF4ROW + jj;
    }

    // Prefetch chunk 0.
    float4 pre[F4PC];
    #pragma unroll
    for (int k = 0; k < F4PC; ++k) pre[k] = capv[gidx[k]];

    float c = 0.0f;

    #pragma unroll
    for (int ch = 0; ch < NCH; ++ch) {
        // Drain prefetch regs -> wave-private LDS (b128, bank-balanced).
        #pragma unroll
        for (int k = 0; k < F4PC; ++k) wt[slot[k]] = pre[k];

        // Issue next chunk's global loads; no barrier will drain them.
        if (ch + 1 < NCH) {
            #pragma unroll
            for (int k = 0; k < F4PC; ++k)
                pre[k] = capv[gidx[k] + (size_t)((ch + 1) * F4PC)];
        }

        // Compute this lane's own row in place (cross-lane data arrived via
        // in-order LDS pipe; wave64 lockstep makes this safe without barrier).
        #pragma unroll
        for (int j = 0; j < F4PC; ++j) {
            float4 x = wt[lane * LROW + j];
            float4 y;
            c = c * decay + x.x;  y.x = sig(x.x, c, vp, kd, invT10);
            c = c * decay + x.y;  y.y = sig(x.y, c, vp, kd, invT10);
            c = c * decay + x.z;  y.z = sig(x.z, c, vp, kd, invT10);
            c = c * decay + x.w;  y.w = sig(x.w, c, vp, kd, invT10);
            wt[lane * LROW + j] = y;
        }

        // Gather back in cooperative order -> fully coalesced 64B-line stores.
        #pragma unroll
        for (int k = 0; k < F4PC; ++k)
            outv[gidx[k] + (size_t)(ch * F4PC)] = wt[slot[k]];
    }
}

extern "C" void kernel_launch(void* const* d_in, const int* in_sizes, int n_in,
                              void* d_out, int out_size, void* d_ws, size_t ws_size,
                              hipStream_t stream) {
    const float* ktrans = (const float*)d_in[0];
    const float* vp     = (const float*)d_in[1];
    const float* ve     = (const float*)d_in[2];
    const float* T10    = (const float*)d_in[3];
    const float* CAp    = (const float*)d_in[4];
    float* out = (float*)d_out;

    dim3 block(256);
    dim3 grid(BATCH / 256);
    etofts_kernel<<<grid, block, 0, stream>>>(ktrans, vp, ve, T10, CAp, out);
}

// Round 5
// 43.795 us; speedup vs baseline: 1.7881x; 1.2013x over previous
//
#include <hip/hip_runtime.h>

#define N_TIME  112
#define BATCH   262144
#define NF4ROW  28      // float4 per row
#define NCH     7       // chunks of 16 cols (4 float4) per row

__device__ __forceinline__ float sig(float cap, float c, float vp,
                                     float kd, float invT10) {
    const float TR     = 0.005f;
    const float R1     = 4.5f;
    const float SINA20 = 20.0f * 0.25881904510252074f;  // 20*sin(15deg)
    const float COSA   = 0.96592582628906829f;          // cos(15deg)
    float ct = vp * cap + kd * c;
    float e  = __expf(-TR * (invT10 + R1 * ct));
    return (1.0f - e) * SINA20 * __builtin_amdgcn_rcpf(1.0f - e * COSA);
}

__global__ __launch_bounds__(256) void etofts_kernel(
    const float* __restrict__ ktrans_p,
    const float* __restrict__ vp_p,
    const float* __restrict__ ve_p,
    const float* __restrict__ T10_p,
    const float* __restrict__ cap_p,
    float* __restrict__ out_p)
{
    const int tid = blockIdx.x * blockDim.x + threadIdx.x;
    const int row = tid >> 2;          // 4 threads per row
    const int t   = tid & 3;           // sub-lane within row (cols t*4 .. t*4+3 of each chunk)

    const float DELTT  = 4.0f / 60.0f;
    const float ktrans = ktrans_p[row];
    const float vp     = vp_p[row];
    const float ve     = ve_p[row];
    const float invT10 = __builtin_amdgcn_rcpf(T10_p[row]);
    const float kd     = ktrans * DELTT;

    const float d1  = __expf(-ktrans / ve * DELTT);   // decay
    const float d2  = d1 * d1;
    const float d3  = d2 * d1;
    const float d4  = d2 * d2;
    const float d8  = d4 * d4;
    const float d12 = d8 * d4;
    const float d16 = d8 * d8;
    const float dt4 = (t == 0) ? 1.0f : (t == 1) ? d4 : (t == 2) ? d8 : d12;

    // Lane's float4 for chunk ch lives at row*28 + ch*4 + t  (64B-line aligned
    // per 4-lane group; every load/store instruction covers 16 full lines).
    const float4* capv = reinterpret_cast<const float4*>(cap_p) + (size_t)row * NF4ROW + t;
    float4*       outv = reinterpret_cast<float4*>(out_p)       + (size_t)row * NF4ROW + t;

    float c_in = 0.0f;   // IIR state entering current chunk (value at previous col)

    // Rolling depth-2 prefetch; no LDS, no barriers -> loads stay in flight.
    float4 xa = capv[0];
    float4 xb = capv[4];

    #pragma unroll
    for (int ch = 0; ch < NCH; ++ch) {
        float4 xf;
        if (ch + 2 < NCH) xf = capv[(ch + 2) * 4];

        const float4 x = xa;

        // Local 4-element scan (zero init).
        float s0 = x.x;
        float s1 = fmaf(d1, s0, x.y);
        float s2 = fmaf(d1, s1, x.z);
        float s3 = fmaf(d1, s2, x.w);

        // Inclusive scan of s3 across the 4-lane group, ratio d4.
        float S  = s3;
        float v1 = __shfl_up(S, 1, 4);
        if (t >= 1) S = fmaf(d4, v1, S);
        float v2 = __shfl_up(S, 2, 4);
        if (t >= 2) S = fmaf(d8, v2, S);

        // Exclusive lane prefix + carry from previous chunk.
        float E   = __shfl_up(S, 1, 4);                 // S_{t-1} (valid t>=1)
        float tin = (t == 0) ? dt4 * c_in : fmaf(dt4, c_in, E);

        // Next chunk's carry = value at this chunk's last col (lane 3's S).
        float S3 = __shfl(S, 3, 4);
        c_in = fmaf(d16, c_in, S3);

        // Final scan values for this lane's 4 columns.
        float c0 = fmaf(d1, tin, s0);
        float c1 = fmaf(d2, tin, s1);
        float c2 = fmaf(d3, tin, s2);
        float c3 = fmaf(d4, tin, s3);

        float4 y;
        y.x = sig(x.x, c0, vp, kd, invT10);
        y.y = sig(x.y, c1, vp, kd, invT10);
        y.z = sig(x.z, c2, vp, kd, invT10);
        y.w = sig(x.w, c3, vp, kd, invT10);
        outv[ch * 4] = y;

        xa = xb;
        xb = xf;
    }
}

extern "C" void kernel_launch(void* const* d_in, const int* in_sizes, int n_in,
                              void* d_out, int out_size, void* d_ws, size_t ws_size,
                              hipStream_t stream) {
    const float* ktrans = (const float*)d_in[0];
    const float* vp     = (const float*)d_in[1];
    const float* ve     = (const float*)d_in[2];
    const float* T10    = (const float*)d_in[3];
    const float* CAp    = (const float*)d_in[4];
    float* out = (float*)d_out;

    dim3 block(256);
    dim3 grid((BATCH * 4) / 256);   // 4 threads per row
    etofts_kernel<<<grid, block, 0, stream>>>(ktrans, vp, ve, T10, CAp, out);
}